// Round 6
// baseline (113.922 us; speedup 1.0000x reference)
//
#include <hip/hip_runtime.h>

#define C2 2.8853900817779268f  // 2*log2(e)
#define DIN 1024
#define HD 512

typedef short short8 __attribute__((ext_vector_type(8)));   // 8 bf16 (4 VGPRs)
typedef float floatx4 __attribute__((ext_vector_type(4)));  // MFMA acc

__device__ __forceinline__ float rcp_fast(float x){ return __builtin_amdgcn_rcpf(x); }
__device__ __forceinline__ float exp2_fast(float x){ return __builtin_amdgcn_exp2f(x); }
__device__ __forceinline__ float comp4(const float4& v, int i){
    return i==0 ? v.x : i==1 ? v.y : i==2 ? v.z : v.w;  // i compile-time under unroll
}
__device__ __forceinline__ unsigned short f2bf(float f){   // RNE fp32->bf16
    union{float f; unsigned int u;} v; v.f = f;
    unsigned int u = v.u;
    return (unsigned short)((u + 0x7FFFu + ((u >> 16) & 1u)) >> 16);
}

// ---------- convert: x, Wh, Wm (fp32) -> bf16 buffers ----------
__global__ __launch_bounds__(256) void convert_kernel(
    const float* __restrict__ x, const float* __restrict__ Wh,
    const float* __restrict__ Wm, unsigned short* __restrict__ xb,
    unsigned short* __restrict__ whb, unsigned short* __restrict__ wmb)
{
    int r = blockIdx.z;
    const float* s = r == 0 ? x : r == 1 ? Wh : Wm;
    unsigned short* d = r == 0 ? xb : r == 1 ? whb : wmb;
    int i = (blockIdx.x * 256 + threadIdx.x) * 4;   // 512 blocks x 256 thr x 4 = 524288
    float4 v = *(const float4*)(s + i);
    ushort4 o = { f2bf(v.x), f2bf(v.y), f2bf(v.z), f2bf(v.w) };
    *(ushort4*)(d + i) = o;
}

// ---------- MFMA gemm + fused exp2 epilogue ----------
// C[s,j] = sum_k x[s,k] * W[j,k];  EH/EM[s,j] = exp2(C2*(C+bias[j]))
// One 16x16 C tile per wave via mfma_f32_16x16x32_bf16, K=1024 in 32-steps.
// A frag: row m=lane&15, k=quad*8+j.  B frag: col n=lane&15 (W row-major = B^T).
// C/D: col=lane&15, row=quad*4+reg  [m89/m120-verified layouts]
__global__ __launch_bounds__(256) void mfma_gemm_kernel(
    const unsigned short* __restrict__ xb, const unsigned short* __restrict__ whb,
    const unsigned short* __restrict__ wmb, const float* __restrict__ bh,
    const float* __restrict__ bm, float* __restrict__ EH, float* __restrict__ EM)
{
    int mat = blockIdx.z;
    const unsigned short* B = mat ? wmb : whb;
    const float* bias = mat ? bm : bh;
    float* O = mat ? EM : EH;
    int j0 = blockIdx.x * 32, s0 = blockIdx.y * 32;
    int wave = threadIdx.x >> 6, lane = threadIdx.x & 63;
    int sw = (wave & 1) * 16, jw = (wave >> 1) * 16;
    int m = lane & 15, quad = lane >> 4;

    const unsigned short* ap = xb + (size_t)(s0 + sw + m) * DIN + quad * 8;
    const unsigned short* bp = B  + (size_t)(j0 + jw + m) * DIN + quad * 8;

    floatx4 acc = {0.f, 0.f, 0.f, 0.f};
    #pragma unroll 8
    for (int k = 0; k < DIN; k += 32){
        short8 af = *(const short8*)(ap + k);
        short8 bf = *(const short8*)(bp + k);
        acc = __builtin_amdgcn_mfma_f32_16x16x32_bf16(af, bf, acc, 0, 0, 0);
    }
    int col = j0 + jw + m;
    float bv = bias[col];
    #pragma unroll
    for (int i = 0; i < 4; i++){
        int row = s0 + sw + quad * 4 + i;
        O[(size_t)row * HD + col] = exp2_fast(C2 * (acc[i] + bv));
    }
}

// ---------- scores (full-d, fused c0 + direct out write) ----------
// out[h,m] = b2 + sum(w2) + sum_d (-2 w2[d]) * rcp(1 + EH[h,d]*EM[m,d])
// 32h x 32m per block (grid 16x16 = 256 blocks, 1/CU), 512 thr (8 waves, 2/SIMD),
// d staged in 64-chunks. Micro: 1h x 2m per thread.
// Hs [h][d] stride 68 (store 2-way free, read broadcast);
// Ms [d][m] stride 34 (store 2 lanes/bank free, read float2 broadcast-aligned).
__global__ __launch_bounds__(512) void scores_kernel(
    const float* __restrict__ EH, const float* __restrict__ EM,
    const float* __restrict__ w2, const float* __restrict__ b2,
    float* __restrict__ out)
{
    int m0 = blockIdx.x * 32, h0 = blockIdx.y * 32;
    __shared__ float Hs[32 * 68];
    __shared__ float Ms[64 * 34];
    __shared__ float wsS[64];
    __shared__ float red[8];
    __shared__ float c0s;
    int tid = threadIdx.x;
    int tx = tid & 15, ty = tid >> 4;   // ty 0..31 = h row; tx = m-pair (2 m)

    // c0 = b2 + sum(w2)
    {
        float s = 0.f;
        if (tid < 128){ float4 v = ((const float4*)w2)[tid]; s = v.x + v.y + v.z + v.w; }
        #pragma unroll
        for (int off = 32; off; off >>= 1) s += __shfl_down(s, off, 64);
        if ((tid & 63) == 0) red[tid >> 6] = s;
        __syncthreads();
        if (tid == 0) c0s = red[0] + red[1] + b2[0];
    }

    float acc0 = 0.f, acc1 = 0.f;
    for (int d0 = 0; d0 < 512; d0 += 64){
        __syncthreads();   // LDS reuse across chunks (also covers c0s write)
        {
            int row = tid >> 4, q = tid & 15;        // Hs: 32 rows x 16 float4
            float4 h = *(const float4*)(EH + (size_t)(h0 + row) * HD + d0 + q * 4);
            *(float4*)&Hs[row * 68 + q * 4] = h;
            int q2 = tid >> 5, mm = tid & 31;        // Ms: 16 q-slots x 32 m
            float4 v = *(const float4*)(EM + (size_t)(m0 + mm) * HD + d0 + q2 * 4);
            Ms[(q2*4 + 0) * 34 + mm] = v.x;
            Ms[(q2*4 + 1) * 34 + mm] = v.y;
            Ms[(q2*4 + 2) * 34 + mm] = v.z;
            Ms[(q2*4 + 3) * 34 + mm] = v.w;
            if (tid < 16){
                float4 w = *(const float4*)(w2 + d0 + tid * 4);
                float4 ws = {-2.f * w.x, -2.f * w.y, -2.f * w.z, -2.f * w.w};
                *(float4*)&wsS[tid * 4] = ws;
            }
        }
        __syncthreads();
        #pragma unroll 4
        for (int it = 0; it < 16; it++){
            int dk = it * 4;
            float4 w4 = *(const float4*)&wsS[dk];
            float4 hA = *(const float4*)&Hs[ty * 68 + dk];
            #pragma unroll
            for (int dd = 0; dd < 4; dd++){
                float2 mv = *(const float2*)&Ms[(dk + dd) * 34 + tx * 2];
                float w = comp4(w4, dd), e = comp4(hA, dd);
                acc0 = fmaf(w, rcp_fast(fmaf(e, mv.x, 1.f)), acc0);
                acc1 = fmaf(w, rcp_fast(fmaf(e, mv.y, 1.f)), acc1);
            }
        }
    }
    float c0v = c0s;
    float2 o = {acc0 + c0v, acc1 + c0v};
    *(float2*)&out[(size_t)(h0 + ty) * 512 + m0 + tx * 2] = o;
}

extern "C" void kernel_launch(void* const* d_in, const int* in_sizes, int n_in,
                              void* d_out, int out_size, void* d_ws, size_t ws_size,
                              hipStream_t stream) {
    const float* x   = (const float*)d_in[0];   // [1,512,1024]
    const float* Wh  = (const float*)d_in[1];   // [512,1024]
    const float* bh  = (const float*)d_in[2];   // [512]
    const float* Wm  = (const float*)d_in[3];   // [512,1024]
    const float* bm  = (const float*)d_in[4];   // [512]
    const float* w2  = (const float*)d_in[5];   // [512]
    const float* b2  = (const float*)d_in[6];   // [1]
    float* out = (float*)d_out;                 // [512,512]
    (void)in_sizes; (void)n_in; (void)out_size; (void)ws_size;

    float* w = (float*)d_ws;
    unsigned short* xb  = (unsigned short*)(w);            // 524288 bf16 = 262144 f
    unsigned short* whb = (unsigned short*)(w + 262144);   // 262144 f
    unsigned short* wmb = (unsigned short*)(w + 524288);   // 262144 f
    float* EH = w + 786432;                                // 262144
    float* EM = w + 1048576;                               // 262144

    convert_kernel<<<dim3(512, 1, 3), 256, 0, stream>>>(x, Wh, Wm, xb, whb, wmb);
    mfma_gemm_kernel<<<dim3(16, 16, 2), 256, 0, stream>>>(xb, whb, wmb, bh, bm, EH, EM);
    scores_kernel<<<dim3(16, 16), 512, 0, stream>>>(EH, EM, w2, b2, out);
}

// Round 7
// 111.701 us; speedup vs baseline: 1.0199x; 1.0199x over previous
//
#include <hip/hip_runtime.h>

#define C2 2.8853900817779268f  // 2*log2(e)
#define DIN 1024
#define HD 512

typedef short short8 __attribute__((ext_vector_type(8)));   // 8 bf16 (4 VGPRs)
typedef float floatx4 __attribute__((ext_vector_type(4)));  // MFMA acc

__device__ __forceinline__ float rcp_fast(float x){ return __builtin_amdgcn_rcpf(x); }
__device__ __forceinline__ float exp2_fast(float x){ return __builtin_amdgcn_exp2f(x); }
__device__ __forceinline__ float comp4(const float4& v, int i){
    return i==0 ? v.x : i==1 ? v.y : i==2 ? v.z : v.w;  // i compile-time under unroll
}
__device__ __forceinline__ unsigned short f2bf(float f){   // RNE fp32->bf16
    union{float f; unsigned int u;} v; v.f = f;
    unsigned int u = v.u;
    return (unsigned short)((u + 0x7FFFu + ((u >> 16) & 1u)) >> 16);
}

// ---------- convert: x, Wh, Wm (fp32) -> bf16 buffers ----------
// Kept separate from the gemm: fusing would re-convert each tile 16x (redundancy
// is inherent to the 16x16 tile grid); once-only conversion is ~1.5 us.
__global__ __launch_bounds__(256) void convert_kernel(
    const float* __restrict__ x, const float* __restrict__ Wh,
    const float* __restrict__ Wm, unsigned short* __restrict__ xb,
    unsigned short* __restrict__ whb, unsigned short* __restrict__ wmb)
{
    int r = blockIdx.z;
    const float* s = r == 0 ? x : r == 1 ? Wh : Wm;
    unsigned short* d = r == 0 ? xb : r == 1 ? whb : wmb;
    int i = (blockIdx.x * 256 + threadIdx.x) * 4;   // 512 blocks x 256 thr x 4 = 524288
    float4 v = *(const float4*)(s + i);
    ushort4 o = { f2bf(v.x), f2bf(v.y), f2bf(v.z), f2bf(v.w) };
    *(ushort4*)(d + i) = o;
}

// ---------- MFMA gemm + fused exp2 epilogue ----------
// C[s,j] = sum_k x[s,k] * W[j,k];  EH/EM[s,j] = exp2(C2*(C+bias[j]))
// One 16x16 C tile per wave via mfma_f32_16x16x32_bf16, K=1024 in 32-steps.
// A frag: row m=lane&15, k=quad*8+j.  B frag: col n=lane&15 (W row-major = B^T).
// C/D: col=lane&15, row=quad*4+reg  [m89/m120-verified layouts]
__global__ __launch_bounds__(256) void mfma_gemm_kernel(
    const unsigned short* __restrict__ xb, const unsigned short* __restrict__ whb,
    const unsigned short* __restrict__ wmb, const float* __restrict__ bh,
    const float* __restrict__ bm, float* __restrict__ EH, float* __restrict__ EM)
{
    int mat = blockIdx.z;
    const unsigned short* B = mat ? wmb : whb;
    const float* bias = mat ? bm : bh;
    float* O = mat ? EM : EH;
    int j0 = blockIdx.x * 32, s0 = blockIdx.y * 32;
    int wave = threadIdx.x >> 6, lane = threadIdx.x & 63;
    int sw = (wave & 1) * 16, jw = (wave >> 1) * 16;
    int m = lane & 15, quad = lane >> 4;

    const unsigned short* ap = xb + (size_t)(s0 + sw + m) * DIN + quad * 8;
    const unsigned short* bp = B  + (size_t)(j0 + jw + m) * DIN + quad * 8;

    floatx4 acc = {0.f, 0.f, 0.f, 0.f};
    #pragma unroll 8
    for (int k = 0; k < DIN; k += 32){
        short8 af = *(const short8*)(ap + k);
        short8 bf = *(const short8*)(bp + k);
        acc = __builtin_amdgcn_mfma_f32_16x16x32_bf16(af, bf, acc, 0, 0, 0);
    }
    int col = j0 + jw + m;
    float bv = bias[col];
    #pragma unroll
    for (int i = 0; i < 4; i++){
        int row = s0 + sw + quad * 4 + i;
        O[(size_t)row * HD + col] = exp2_fast(C2 * (acc[i] + bv));
    }
}

// ---------- scores (full-d, fused c0, direct out) ----------
// out[h,m] = b2 + sum(w2) + sum_d (-2 w2[d]) * rcp(1 + EH[h,d]*EM[m,d])
// 16h x 32m per block, 256 thr (4 waves), grid (16 m-tiles, 32 h-tiles) = 512
// blocks = 2 blocks/CU -> cross-block overlap of the per-chunk barrier stalls
// (R6's 1 block/CU exposed them). Micro: 1h x 2m. Trans-pipe bound:
// 1024 rcp/thread, 56 LDS cyc vs 64 trans cyc per inner it.
// Hs [h][d] stride 68; Ms [d][m] stride 34 — all accesses <=2-way (free).
__global__ __launch_bounds__(256) void scores_kernel(
    const float* __restrict__ EH, const float* __restrict__ EM,
    const float* __restrict__ w2, const float* __restrict__ b2,
    float* __restrict__ out)
{
    int m0 = blockIdx.x * 32, h0 = blockIdx.y * 16;
    __shared__ float Hs[16 * 68];
    __shared__ float Ms[64 * 34];
    __shared__ float wsS[64];
    __shared__ float red[4];
    __shared__ float c0s;
    int tid = threadIdx.x;
    int tx = tid & 15, ty = tid >> 4;   // ty 0..15 = h row; tx = m-pair (2 m)

    // c0 = b2 + sum(w2)
    {
        float s = 0.f;
        if (tid < 128){ float4 v = ((const float4*)w2)[tid]; s = v.x + v.y + v.z + v.w; }
        #pragma unroll
        for (int off = 32; off; off >>= 1) s += __shfl_down(s, off, 64);
        if ((tid & 63) == 0) red[tid >> 6] = s;
        __syncthreads();
        if (tid == 0) c0s = red[0] + red[1] + b2[0];
    }

    float acc0 = 0.f, acc1 = 0.f;
    for (int d0 = 0; d0 < 512; d0 += 64){
        __syncthreads();   // LDS reuse across chunks (also orders c0s write)
        {
            int row = tid >> 4, q = tid & 15;        // Hs: 16 rows x 16 float4
            float4 h = *(const float4*)(EH + (size_t)(h0 + row) * HD + d0 + q * 4);
            *(float4*)&Hs[row * 68 + q * 4] = h;
            int mm = tid & 31;                        // Ms: 16 q-slots x 32 m
            #pragma unroll
            for (int l = 0; l < 2; l++){
                int q2 = (tid >> 5) + 8 * l;          // d-quad 0..15
                float4 v = *(const float4*)(EM + (size_t)(m0 + mm) * HD + d0 + q2 * 4);
                Ms[(q2*4 + 0) * 34 + mm] = v.x;
                Ms[(q2*4 + 1) * 34 + mm] = v.y;
                Ms[(q2*4 + 2) * 34 + mm] = v.z;
                Ms[(q2*4 + 3) * 34 + mm] = v.w;
            }
            if (tid < 16){
                float4 w = *(const float4*)(w2 + d0 + tid * 4);
                float4 ws = {-2.f * w.x, -2.f * w.y, -2.f * w.z, -2.f * w.w};
                *(float4*)&wsS[tid * 4] = ws;
            }
        }
        __syncthreads();
        #pragma unroll 4
        for (int it = 0; it < 16; it++){
            int dk = it * 4;
            float4 w4 = *(const float4*)&wsS[dk];
            float4 hA = *(const float4*)&Hs[ty * 68 + dk];
            #pragma unroll
            for (int dd = 0; dd < 4; dd++){
                float2 mv = *(const float2*)&Ms[(dk + dd) * 34 + tx * 2];
                float w = comp4(w4, dd), e = comp4(hA, dd);
                acc0 = fmaf(w, rcp_fast(fmaf(e, mv.x, 1.f)), acc0);
                acc1 = fmaf(w, rcp_fast(fmaf(e, mv.y, 1.f)), acc1);
            }
        }
    }
    float c0v = c0s;
    float2 o = {acc0 + c0v, acc1 + c0v};
    *(float2*)&out[(size_t)(h0 + ty) * 512 + m0 + tx * 2] = o;
}

extern "C" void kernel_launch(void* const* d_in, const int* in_sizes, int n_in,
                              void* d_out, int out_size, void* d_ws, size_t ws_size,
                              hipStream_t stream) {
    const float* x   = (const float*)d_in[0];   // [1,512,1024]
    const float* Wh  = (const float*)d_in[1];   // [512,1024]
    const float* bh  = (const float*)d_in[2];   // [512]
    const float* Wm  = (const float*)d_in[3];   // [512,1024]
    const float* bm  = (const float*)d_in[4];   // [512]
    const float* w2  = (const float*)d_in[5];   // [512]
    const float* b2  = (const float*)d_in[6];   // [1]
    float* out = (float*)d_out;                 // [512,512]
    (void)in_sizes; (void)n_in; (void)out_size; (void)ws_size;

    float* w = (float*)d_ws;
    unsigned short* xb  = (unsigned short*)(w);            // 524288 bf16 = 262144 f
    unsigned short* whb = (unsigned short*)(w + 262144);   // 262144 f
    unsigned short* wmb = (unsigned short*)(w + 524288);   // 262144 f
    float* EH = w + 786432;                                // 262144
    float* EM = w + 1048576;                               // 262144

    convert_kernel<<<dim3(512, 1, 3), 256, 0, stream>>>(x, Wh, Wm, xb, whb, wmb);
    mfma_gemm_kernel<<<dim3(16, 16, 2), 256, 0, stream>>>(xb, whb, wmb, bh, bm, EH, EM);
    scores_kernel<<<dim3(16, 32), 256, 0, stream>>>(EH, EM, w2, b2, out);
}

// Round 8
// 109.262 us; speedup vs baseline: 1.0427x; 1.0223x over previous
//
#include <hip/hip_runtime.h>

#define C2 2.8853900817779268f  // 2*log2(e)
#define DIN 1024
#define HD 512

typedef short short8 __attribute__((ext_vector_type(8)));   // 8 bf16 (4 VGPRs)
typedef float floatx4 __attribute__((ext_vector_type(4)));  // MFMA acc

__device__ __forceinline__ float rcp_fast(float x){ return __builtin_amdgcn_rcpf(x); }
__device__ __forceinline__ float exp2_fast(float x){ return __builtin_amdgcn_exp2f(x); }
__device__ __forceinline__ float comp4(const float4& v, int i){
    return i==0 ? v.x : i==1 ? v.y : i==2 ? v.z : v.w;  // i compile-time under unroll
}
__device__ __forceinline__ unsigned short f2bf(float f){   // RNE fp32->bf16
    union{float f; unsigned int u;} v; v.f = f;
    unsigned int u = v.u;
    return (unsigned short)((u + 0x7FFFu + ((u >> 16) & 1u)) >> 16);
}

// ---------- convert: x, Wh, Wm (fp32) -> bf16 buffers ----------
__global__ __launch_bounds__(256) void convert_kernel(
    const float* __restrict__ x, const float* __restrict__ Wh,
    const float* __restrict__ Wm, unsigned short* __restrict__ xb,
    unsigned short* __restrict__ whb, unsigned short* __restrict__ wmb)
{
    int r = blockIdx.z;
    const float* s = r == 0 ? x : r == 1 ? Wh : Wm;
    unsigned short* d = r == 0 ? xb : r == 1 ? whb : wmb;
    int i = (blockIdx.x * 256 + threadIdx.x) * 4;   // 512 blocks x 256 thr x 4 = 524288
    float4 v = *(const float4*)(s + i);
    ushort4 o = { f2bf(v.x), f2bf(v.y), f2bf(v.z), f2bf(v.w) };
    *(ushort4*)(d + i) = o;
}

// ---------- MFMA gemm + fused exp2 epilogue ----------
// C[s,j] = sum_k x[s,k] * W[j,k];  EH/EM[s,j] = exp2(C2*(C+bias[j]))
// One 16x16 C tile per wave via mfma_f32_16x16x32_bf16, K=1024 in 32-steps.
// A frag: row m=lane&15, k=quad*8+j.  B frag: col n=lane&15 (W row-major = B^T).
// C/D: col=lane&15, row=quad*4+reg  [m89/m120-verified layouts]
__global__ __launch_bounds__(256) void mfma_gemm_kernel(
    const unsigned short* __restrict__ xb, const unsigned short* __restrict__ whb,
    const unsigned short* __restrict__ wmb, const float* __restrict__ bh,
    const float* __restrict__ bm, float* __restrict__ EH, float* __restrict__ EM)
{
    int mat = blockIdx.z;
    const unsigned short* B = mat ? wmb : whb;
    const float* bias = mat ? bm : bh;
    float* O = mat ? EM : EH;
    int j0 = blockIdx.x * 32, s0 = blockIdx.y * 32;
    int wave = threadIdx.x >> 6, lane = threadIdx.x & 63;
    int sw = (wave & 1) * 16, jw = (wave >> 1) * 16;
    int m = lane & 15, quad = lane >> 4;

    const unsigned short* ap = xb + (size_t)(s0 + sw + m) * DIN + quad * 8;
    const unsigned short* bp = B  + (size_t)(j0 + jw + m) * DIN + quad * 8;

    floatx4 acc = {0.f, 0.f, 0.f, 0.f};
    #pragma unroll 8
    for (int k = 0; k < DIN; k += 32){
        short8 af = *(const short8*)(ap + k);
        short8 bf = *(const short8*)(bp + k);
        acc = __builtin_amdgcn_mfma_f32_16x16x32_bf16(af, bf, acc, 0, 0, 0);
    }
    int col = j0 + jw + m;
    float bv = bias[col];
    #pragma unroll
    for (int i = 0; i < 4; i++){
        int row = s0 + sw + quad * 4 + i;
        O[(size_t)row * HD + col] = exp2_fast(C2 * (acc[i] + bv));
    }
}

// ---------- scores partial: Q[ds][h][m] = sum_{d in slice} (-2 w2[d]) * rcp(1+EH[h,d]*EM[m,d])
// 32h x 64m x 64d blocks (1024 blocks, 4/CU), 256 thr, 2x4 micro.
// Single load->sync->compute phase per block (no in-loop barriers) — empirically
// the fastest scores variant (R5); fused full-d versions (R6/R7) regressed.
__global__ __launch_bounds__(256, 4) void scores_kernel(
    const float* __restrict__ EH, const float* __restrict__ EM,
    const float* __restrict__ w2, float* __restrict__ Q)
{
    int m0 = blockIdx.x * 64, h0 = blockIdx.y * 32, d0 = blockIdx.z * 64;
    __shared__ float Hs[32 * 68];
    __shared__ float Ms[64 * 68];
    __shared__ float wsS[64];
    int tid = threadIdx.x;
    int tx = tid & 15, ty = tid >> 4;   // tx: m-group (x4), ty: h-group (x2)
    #pragma unroll
    for (int l = 0; l < 2; l++){        // Hs: 32 rows x 16 float4
        int slot = tid + 256 * l;
        int row = slot >> 4, q = slot & 15;
        float4 h = *(const float4*)(EH + (size_t)(h0 + row) * HD + d0 + q * 4);
        *(float4*)&Hs[row * 68 + q * 4] = h;
    }
    #pragma unroll
    for (int l = 0; l < 4; l++){        // Ms: 64 m-rows x 16 float4, transposed scatter
        int slot = tid + 256 * l;
        int mm = slot >> 4, q = slot & 15;
        float4 v = *(const float4*)(EM + (size_t)(m0 + mm) * HD + d0 + q * 4);
        Ms[(q*4 + 0) * 68 + mm] = v.x;
        Ms[(q*4 + 1) * 68 + mm] = v.y;
        Ms[(q*4 + 2) * 68 + mm] = v.z;
        Ms[(q*4 + 3) * 68 + mm] = v.w;
    }
    if (tid < 16){
        float4 w = *(const float4*)(w2 + d0 + tid * 4);
        float4 ws = {-2.f * w.x, -2.f * w.y, -2.f * w.z, -2.f * w.w};
        *(float4*)&wsS[tid * 4] = ws;
    }
    __syncthreads();

    float acc[2][4] = {};
    #pragma unroll 2
    for (int it = 0; it < 16; it++){
        int dk = it * 4;
        float4 w4 = *(const float4*)&wsS[dk];
        float4 hA = *(const float4*)&Hs[(ty*2 + 0) * 68 + dk];
        float4 hB = *(const float4*)&Hs[(ty*2 + 1) * 68 + dk];
        #pragma unroll
        for (int dd = 0; dd < 4; dd++){
            float4 mv = *(const float4*)&Ms[(dk + dd) * 68 + tx * 4];
            float w = comp4(w4, dd);
            float e0 = comp4(hA, dd), e1 = comp4(hB, dd);
            acc[0][0] = fmaf(w, rcp_fast(fmaf(e0, mv.x, 1.f)), acc[0][0]);
            acc[0][1] = fmaf(w, rcp_fast(fmaf(e0, mv.y, 1.f)), acc[0][1]);
            acc[0][2] = fmaf(w, rcp_fast(fmaf(e0, mv.z, 1.f)), acc[0][2]);
            acc[0][3] = fmaf(w, rcp_fast(fmaf(e0, mv.w, 1.f)), acc[0][3]);
            acc[1][0] = fmaf(w, rcp_fast(fmaf(e1, mv.x, 1.f)), acc[1][0]);
            acc[1][1] = fmaf(w, rcp_fast(fmaf(e1, mv.y, 1.f)), acc[1][1]);
            acc[1][2] = fmaf(w, rcp_fast(fmaf(e1, mv.z, 1.f)), acc[1][2]);
            acc[1][3] = fmaf(w, rcp_fast(fmaf(e1, mv.w, 1.f)), acc[1][3]);
        }
    }
    float* Qp = Q + (size_t)blockIdx.z * 262144;
    #pragma unroll
    for (int i = 0; i < 2; i++){
        float4 v = {acc[i][0], acc[i][1], acc[i][2], acc[i][3]};
        *(float4*)&Qp[(h0 + ty*2 + i) * 512 + m0 + tx * 4] = v;
    }
}

// ---------- combine: out = c0 + sum of 8 d-slice partials, c0 = b2 + sum(w2)
__global__ __launch_bounds__(256) void combine_kernel(
    const float* __restrict__ Q, const float* __restrict__ w2,
    const float* __restrict__ b2, float* __restrict__ out)
{
    int tid = threadIdx.x;
    __shared__ float red[4];
    __shared__ float c0s;
    float s = 0.f;
    if (tid < 128){ float4 v = ((const float4*)w2)[tid]; s = v.x + v.y + v.z + v.w; }
    #pragma unroll
    for (int off = 32; off; off >>= 1) s += __shfl_down(s, off, 64);
    if (tid < 128 && (tid & 63) == 0) red[tid >> 6] = s;
    __syncthreads();
    if (tid == 0) c0s = red[0] + red[1] + b2[0];
    __syncthreads();
    float c0 = c0s;
    int g = blockIdx.x * 256 + tid;
    const float4* Q4 = (const float4*)Q;
    float4 a = Q4[g];
    #pragma unroll
    for (int sl = 1; sl < 8; sl++){
        float4 b = Q4[sl * 65536 + g];
        a.x += b.x; a.y += b.y; a.z += b.z; a.w += b.w;
    }
    float4 o = {a.x + c0, a.y + c0, a.z + c0, a.w + c0};
    ((float4*)out)[g] = o;
}

extern "C" void kernel_launch(void* const* d_in, const int* in_sizes, int n_in,
                              void* d_out, int out_size, void* d_ws, size_t ws_size,
                              hipStream_t stream) {
    const float* x   = (const float*)d_in[0];   // [1,512,1024]
    const float* Wh  = (const float*)d_in[1];   // [512,1024]
    const float* bh  = (const float*)d_in[2];   // [512]
    const float* Wm  = (const float*)d_in[3];   // [512,1024]
    const float* bm  = (const float*)d_in[4];   // [512]
    const float* w2  = (const float*)d_in[5];   // [512]
    const float* b2  = (const float*)d_in[6];   // [1]
    float* out = (float*)d_out;                 // [512,512]
    (void)in_sizes; (void)n_in; (void)out_size; (void)ws_size;

    float* w = (float*)d_ws;
    unsigned short* xb  = (unsigned short*)(w);            // 524288 bf16 = 262144 f
    unsigned short* whb = (unsigned short*)(w + 262144);   // 262144 f
    unsigned short* wmb = (unsigned short*)(w + 524288);   // 262144 f
    float* EH = w + 786432;                                // 262144
    float* EM = w + 1048576;                               // 262144
    float* Q  = w + 1310720;                               // 8 * 262144

    convert_kernel<<<dim3(512, 1, 3), 256, 0, stream>>>(x, Wh, Wm, xb, whb, wmb);
    mfma_gemm_kernel<<<dim3(16, 16, 2), 256, 0, stream>>>(xb, whb, wmb, bh, bm, EH, EM);
    scores_kernel<<<dim3(8, 16, 8), 256, 0, stream>>>(EH, EM, w2, Q);
    combine_kernel<<<256, 256, 0, stream>>>(Q, w2, b2, out);
}